// Round 12
// baseline (247.655 us; speedup 1.0000x reference)
//
#include <hip/hip_runtime.h>

#define D_DIM 160
#define H_DIM 192
#define W_DIM 160
#define NVOX (D_DIM * H_DIM * W_DIM)

typedef _Float16 half_t;
typedef __attribute__((ext_vector_type(4))) _Float16 H4;  // x,y,z,pad : 8 bytes
typedef __attribute__((ext_vector_type(8))) _Float16 H8;  // two voxels : 16 B
typedef __attribute__((ext_vector_type(2))) float F2;     // 8 B fp32 pair

struct F3 {
    float x, y, z;
};

// XCD-chunked remap: contiguous chunk per XCD -> L2-local sweep.
__device__ __forceinline__ int swz_bid(int bid, int nwg) {
    int chunk = nwg >> 3;  // nwg divisible by 8
    return (bid & 7) * chunk + (bid >> 3);
}

// vec (fp32 AoS, float4-vectorized) * 1/128 -> fp16 H4 state. 4 voxels/thread.
// NT stores: dst not re-read from L2 (next kernel sweeps it from L3 anyway).
__global__ __launch_bounds__(256) void scale_to_h(const float4* __restrict__ in,
                                                  H4* __restrict__ out, int n) {
    int i = blockIdx.x * blockDim.x + threadIdx.x;
    if (i >= n) return;
    float4 a = in[3 * i + 0];
    float4 b = in[3 * i + 1];
    float4 c = in[3 * i + 2];
    const float s = 0.0078125f;
    H4 o0 = {(half_t)(a.x * s), (half_t)(a.y * s), (half_t)(a.z * s), (half_t)0.f};
    H4 o1 = {(half_t)(a.w * s), (half_t)(b.x * s), (half_t)(b.y * s), (half_t)0.f};
    H4 o2 = {(half_t)(b.z * s), (half_t)(b.w * s), (half_t)(c.x * s), (half_t)0.f};
    H4 o3 = {(half_t)(c.y * s), (half_t)(c.z * s), (half_t)(c.w * s), (half_t)0.f};
    __builtin_nontemporal_store(o0, out + 4 * i + 0);
    __builtin_nontemporal_store(o1, out + 4 * i + 1);
    __builtin_nontemporal_store(o2, out + 4 * i + 2);
    __builtin_nontemporal_store(o3, out + 4 * i + 3);
}

// One voxel's trilinear gather (fp16 state, fp32 math). Adds flow at the end.
__device__ __forceinline__ void warp_voxel(const H4* __restrict__ v, int d, int h,
                                           int w, float fx, float fy, float fz,
                                           float& r0, float& r1, float& r2) {
    float ld = fminf(fmaxf((float)d + fx, 0.0f), (float)(D_DIM - 1));
    float lh = fminf(fmaxf((float)h + fy, 0.0f), (float)(H_DIM - 1));
    float lw = fminf(fmaxf((float)w + fz, 0.0f), (float)(W_DIM - 1));

    float fd = floorf(ld), fh = floorf(lh), fw = floorf(lw);
    int d0 = (int)fd, h0 = (int)fh, w0 = (int)fw;
    int d1 = min(d0 + 1, D_DIM - 1);
    int h1 = min(h0 + 1, H_DIM - 1);

    float wd = ld - fd, wh = lh - fh, ww = lw - fw;
    float od = 1.0f - wd, oh = 1.0f - wh, ow = 1.0f - ww;

    // edge trick on weights: at w0==W-1 (ww==0), pair base shifts to W-2 and
    // the whole w-interp weight moves onto the hi element.
    bool hi_edge = (w0 == W_DIM - 1);
    int b = min(w0, W_DIM - 2);
    float owe = hi_edge ? 0.0f : ow;
    float wwe = hi_edge ? ow : ww;

    int r00 = (d0 * H_DIM + h0) * W_DIM + b;
    int r01 = (d0 * H_DIM + h1) * W_DIM + b;
    int r10 = (d1 * H_DIM + h0) * W_DIM + b;
    int r11 = (d1 * H_DIM + h1) * W_DIM + b;

    float acc0 = 0.0f, acc1 = 0.0f, acc2 = 0.0f;
#define CORNER_PAIR(ROW, FAC)                                   \
    {                                                           \
        H8 pr = *reinterpret_cast<const H8*>(v + (ROW));        \
        float wlo = (FAC)*owe, whi = (FAC)*wwe;                 \
        acc0 = fmaf(wlo, (float)pr[0], acc0);                   \
        acc1 = fmaf(wlo, (float)pr[1], acc1);                   \
        acc2 = fmaf(wlo, (float)pr[2], acc2);                   \
        acc0 = fmaf(whi, (float)pr[4], acc0);                   \
        acc1 = fmaf(whi, (float)pr[5], acc1);                   \
        acc2 = fmaf(whi, (float)pr[6], acc2);                   \
    }
    CORNER_PAIR(r00, od * oh);
    CORNER_PAIR(r01, od * wh);
    CORNER_PAIR(r10, wd * oh);
    CORNER_PAIR(r11, wd * wh);
#undef CORNER_PAIR

    r0 = fx + acc0;
    r1 = fy + acc1;
    r2 = fz + acc2;
}

// One scaling-and-squaring step. 2 w-adjacent voxels per thread, 1024-thread
// blocks (contiguous 2048-voxel segment -> L1-resident gather windows).
// MODE 1: fp16 -> fp16.  MODE 2: fp16 -> fp32 AoS (final step into d_out).
// Stores are non-temporal: dst is never read in-pass; keeps L2 for src reuse.
template <int MODE>
__global__ __launch_bounds__(1024) void warp_h(const H4* __restrict__ v,
                                               void* __restrict__ outp) {
    int wg = swz_bid(blockIdx.x, gridDim.x);
    int base = wg * 2048 + (int)threadIdx.x * 2;  // even voxel index

    int w = base % W_DIM;  // even, so w+1 stays in the same row
    int t = base / W_DIM;
    int h = t % H_DIM;
    int d = t / H_DIM;

    H8 fl = *reinterpret_cast<const H8*>(v + base);  // flows for both voxels

    float a0, a1, a2, b0, b1, b2;
    warp_voxel(v, d, h, w, (float)fl[0], (float)fl[1], (float)fl[2], a0, a1, a2);
    warp_voxel(v, d, h, w + 1, (float)fl[4], (float)fl[5], (float)fl[6], b0, b1, b2);

    if (MODE == 1) {
        H8 o = {(half_t)a0, (half_t)a1, (half_t)a2, (half_t)0.f,
                (half_t)b0, (half_t)b1, (half_t)b2, (half_t)0.f};
        __builtin_nontemporal_store(
            o, reinterpret_cast<H8*>(reinterpret_cast<H4*>(outp) + base));
    } else {
        // 2 voxels * 12 B = 24 B at 8 B alignment -> three F2 stores
        F2* o = reinterpret_cast<F2*>(reinterpret_cast<F3*>(outp) + base);
        __builtin_nontemporal_store(F2{a0, a1}, o + 0);
        __builtin_nontemporal_store(F2{a2, b0}, o + 1);
        __builtin_nontemporal_store(F2{b1, b2}, o + 2);
    }
}

extern "C" void kernel_launch(void* const* d_in, const int* in_sizes, int n_in,
                              void* d_out, int out_size, void* d_ws, size_t ws_size,
                              hipStream_t stream) {
    const float* vec = (const float*)d_in[0];
    H4* W = (H4*)d_ws;   // fp16 state in workspace (39.3 MB)
    H4* Q = (H4*)d_out;  // d_out doubles as fp16 scratch mid-flight

    // scale: vec/128 -> W (fp16)
    scale_to_h<<<(NVOX / 4 + 255) / 256, 256, 0, stream>>>(
        (const float4*)vec, W, NVOX / 4);

    int grid = NVOX / 2048;  // 2400, divisible by 8

    // 7 warp steps: W->Q->W->Q->W->Q->W->(fp32)d_out
    warp_h<1><<<grid, 1024, 0, stream>>>(W, Q);
    warp_h<1><<<grid, 1024, 0, stream>>>(Q, W);
    warp_h<1><<<grid, 1024, 0, stream>>>(W, Q);
    warp_h<1><<<grid, 1024, 0, stream>>>(Q, W);
    warp_h<1><<<grid, 1024, 0, stream>>>(W, Q);
    warp_h<1><<<grid, 1024, 0, stream>>>(Q, W);
    warp_h<2><<<grid, 1024, 0, stream>>>(W, d_out);  // final: fp32 AoS
}

// Round 13
// 184.428 us; speedup vs baseline: 1.3428x; 1.3428x over previous
//
#include <hip/hip_runtime.h>

#define D_DIM 160
#define H_DIM 192
#define W_DIM 160
#define NVOX (D_DIM * H_DIM * W_DIM)

typedef _Float16 half_t;
typedef __attribute__((ext_vector_type(4))) _Float16 H4;  // x,y,z,pad : 8 bytes
typedef __attribute__((ext_vector_type(8))) _Float16 H8;  // two voxels : 16 B

struct F3 {
    float x, y, z;
};

// XCD-chunked remap: contiguous chunk per XCD -> L2-local sweep.
__device__ __forceinline__ int swz_bid(int bid, int nwg) {
    int chunk = nwg >> 3;  // nwg divisible by 8
    return (bid & 7) * chunk + (bid >> 3);
}

// vec (fp32 AoS, float4-vectorized) * 1/128 -> fp16 H4 state. 4 voxels/thread.
__global__ __launch_bounds__(256) void scale_to_h(const float4* __restrict__ in,
                                                  H4* __restrict__ out, int n) {
    int i = blockIdx.x * blockDim.x + threadIdx.x;
    if (i >= n) return;
    float4 a = in[3 * i + 0];
    float4 b = in[3 * i + 1];
    float4 c = in[3 * i + 2];
    const float s = 0.0078125f;
    H4 o0 = {(half_t)(a.x * s), (half_t)(a.y * s), (half_t)(a.z * s), (half_t)0.f};
    H4 o1 = {(half_t)(a.w * s), (half_t)(b.x * s), (half_t)(b.y * s), (half_t)0.f};
    H4 o2 = {(half_t)(b.z * s), (half_t)(b.w * s), (half_t)(c.x * s), (half_t)0.f};
    H4 o3 = {(half_t)(c.y * s), (half_t)(c.z * s), (half_t)(c.w * s), (half_t)0.f};
    out[4 * i + 0] = o0;
    out[4 * i + 1] = o1;
    out[4 * i + 2] = o2;
    out[4 * i + 3] = o3;
}

// One voxel's trilinear gather (fp16 state, fp32 math). Adds flow at the end.
__device__ __forceinline__ void warp_voxel(const H4* __restrict__ v, int d, int h,
                                           int w, float fx, float fy, float fz,
                                           float& r0, float& r1, float& r2) {
    float ld = fminf(fmaxf((float)d + fx, 0.0f), (float)(D_DIM - 1));
    float lh = fminf(fmaxf((float)h + fy, 0.0f), (float)(H_DIM - 1));
    float lw = fminf(fmaxf((float)w + fz, 0.0f), (float)(W_DIM - 1));

    float fd = floorf(ld), fh = floorf(lh), fw = floorf(lw);
    int d0 = (int)fd, h0 = (int)fh, w0 = (int)fw;
    int d1 = min(d0 + 1, D_DIM - 1);
    int h1 = min(h0 + 1, H_DIM - 1);

    float wd = ld - fd, wh = lh - fh, ww = lw - fw;
    float od = 1.0f - wd, oh = 1.0f - wh, ow = 1.0f - ww;

    // edge trick on weights: at w0==W-1 (ww==0), pair base shifts to W-2 and
    // the whole w-interp weight moves onto the hi element.
    bool hi_edge = (w0 == W_DIM - 1);
    int b = min(w0, W_DIM - 2);
    float owe = hi_edge ? 0.0f : ow;
    float wwe = hi_edge ? ow : ww;

    int r00 = (d0 * H_DIM + h0) * W_DIM + b;
    int r01 = (d0 * H_DIM + h1) * W_DIM + b;
    int r10 = (d1 * H_DIM + h0) * W_DIM + b;
    int r11 = (d1 * H_DIM + h1) * W_DIM + b;

    float acc0 = 0.0f, acc1 = 0.0f, acc2 = 0.0f;
#define CORNER_PAIR(ROW, FAC)                                   \
    {                                                           \
        H8 pr = *reinterpret_cast<const H8*>(v + (ROW));        \
        float wlo = (FAC)*owe, whi = (FAC)*wwe;                 \
        acc0 = fmaf(wlo, (float)pr[0], acc0);                   \
        acc1 = fmaf(wlo, (float)pr[1], acc1);                   \
        acc2 = fmaf(wlo, (float)pr[2], acc2);                   \
        acc0 = fmaf(whi, (float)pr[4], acc0);                   \
        acc1 = fmaf(whi, (float)pr[5], acc1);                   \
        acc2 = fmaf(whi, (float)pr[6], acc2);                   \
    }
    CORNER_PAIR(r00, od * oh);
    CORNER_PAIR(r01, od * wh);
    CORNER_PAIR(r10, wd * oh);
    CORNER_PAIR(r11, wd * wh);
#undef CORNER_PAIR

    r0 = fx + acc0;
    r1 = fy + acc1;
    r2 = fz + acc2;
}

// One scaling-and-squaring step. 2 w-adjacent voxels per thread, 1024-thread
// blocks (contiguous 2048-voxel segment -> L1-resident gather windows).
// MODE 1: fp16 -> fp16.  MODE 2: fp16 -> fp32 AoS (final step into d_out).
template <int MODE>
__global__ __launch_bounds__(1024) void warp_h(const H4* __restrict__ v,
                                               void* __restrict__ outp) {
    int wg = swz_bid(blockIdx.x, gridDim.x);
    int base = wg * 2048 + (int)threadIdx.x * 2;  // even voxel index

    int w = base % W_DIM;  // even, so w+1 stays in the same row
    int t = base / W_DIM;
    int h = t % H_DIM;
    int d = t / H_DIM;

    H8 fl = *reinterpret_cast<const H8*>(v + base);  // flows for both voxels

    float a0, a1, a2, b0, b1, b2;
    warp_voxel(v, d, h, w, (float)fl[0], (float)fl[1], (float)fl[2], a0, a1, a2);
    warp_voxel(v, d, h, w + 1, (float)fl[4], (float)fl[5], (float)fl[6], b0, b1, b2);

    if (MODE == 1) {
        H8 o = {(half_t)a0, (half_t)a1, (half_t)a2, (half_t)0.f,
                (half_t)b0, (half_t)b1, (half_t)b2, (half_t)0.f};
        *reinterpret_cast<H8*>(reinterpret_cast<H4*>(outp) + base) = o;
    } else {
        F3* o = reinterpret_cast<F3*>(outp);
        o[base] = F3{a0, a1, a2};
        o[base + 1] = F3{b0, b1, b2};
    }
}

extern "C" void kernel_launch(void* const* d_in, const int* in_sizes, int n_in,
                              void* d_out, int out_size, void* d_ws, size_t ws_size,
                              hipStream_t stream) {
    const float* vec = (const float*)d_in[0];
    H4* W = (H4*)d_ws;   // fp16 state in workspace (39.3 MB)
    H4* Q = (H4*)d_out;  // d_out doubles as fp16 scratch mid-flight

    // scale: vec/128 -> W (fp16)
    scale_to_h<<<(NVOX / 4 + 255) / 256, 256, 0, stream>>>(
        (const float4*)vec, W, NVOX / 4);

    int grid = NVOX / 2048;  // 2400, divisible by 8

    // 7 warp steps: W->Q->W->Q->W->Q->W->(fp32)d_out
    warp_h<1><<<grid, 1024, 0, stream>>>(W, Q);
    warp_h<1><<<grid, 1024, 0, stream>>>(Q, W);
    warp_h<1><<<grid, 1024, 0, stream>>>(W, Q);
    warp_h<1><<<grid, 1024, 0, stream>>>(Q, W);
    warp_h<1><<<grid, 1024, 0, stream>>>(W, Q);
    warp_h<1><<<grid, 1024, 0, stream>>>(Q, W);
    warp_h<2><<<grid, 1024, 0, stream>>>(W, d_out);  // final: fp32 AoS
}